// Round 14
// baseline (224.864 us; speedup 1.0000x reference)
//
#include <hip/hip_runtime.h>
#include <math.h>

// ws offsets (floats)
#define OFF_Q    0
#define OFF_K    (524288)
#define OFF_V    (524288*2)
#define OFF_G    (524288*3)
#define OFF_PRE  (524288*4)

// ---------- DPP helpers ----------
template <int CTRL>
__device__ __forceinline__ float dpp_mov(float x) {
  return __int_as_float(__builtin_amdgcn_update_dpp(0, __float_as_int(x), CTRL, 0xF, 0xF, true));
}
template <int CTRL>
__device__ __forceinline__ float dpp_add(float x) { return x + dpp_mov<CTRL>(x); }
__device__ __forceinline__ float red16(float v) {
  v = dpp_add<0xB1>(v);    // xor 1
  v = dpp_add<0x4E>(v);    // xor 2
  v = dpp_add<0x141>(v);   // row_half_mirror (xor 7)
  v = dpp_add<0x140>(v);   // row_mirror      (xor 15)
  return v;
}

#define SEL8(a, f, out) do { \
  float _s0 = ((f)&1) ? a[1] : a[0]; \
  float _s1 = ((f)&1) ? a[3] : a[2]; \
  float _s2 = ((f)&1) ? a[5] : a[4]; \
  float _s3 = ((f)&1) ? a[7] : a[6]; \
  float _t0 = ((f)&2) ? _s1 : _s0; \
  float _t1 = ((f)&2) ? _s3 : _s2; \
  out = ((f)&4) ? _t1 : _t0; \
} while(0)

__device__ __forceinline__ float4 sel8_f4(const float4* a, int f) {
  float4 s0 = (f&1) ? a[1] : a[0];
  float4 s1 = (f&1) ? a[3] : a[2];
  float4 s2 = (f&1) ? a[5] : a[4];
  float4 s3 = (f&1) ? a[7] : a[6];
  float4 t0 = (f&2) ? s1 : s0;
  float4 t1 = (f&2) ? s3 : s2;
  return (f&4) ? t1 : t0;
}

__device__ __forceinline__ float dot4(float4 a, float4 b, float acc) {
  acc = fmaf(a.x, b.x, acc); acc = fmaf(a.y, b.y, acc);
  acc = fmaf(a.z, b.z, acc); return fmaf(a.w, b.w, acc);
}

template <int CTRL>
__device__ __forceinline__ void merge_dpp(float& m, float& l, float4* acc) {
  float m2 = dpp_mov<CTRL>(m);
  float l2 = dpp_mov<CTRL>(l);
  float M = fmaxf(m, m2);
  float ea = __expf(m - M), eb = __expf(m2 - M);
  l = l*ea + l2*eb;
#pragma unroll
  for (int x = 0; x < 8; ++x) {
    acc[x].x = acc[x].x*ea + dpp_mov<CTRL>(acc[x].x)*eb;
    acc[x].y = acc[x].y*ea + dpp_mov<CTRL>(acc[x].y)*eb;
    acc[x].z = acc[x].z*ea + dpp_mov<CTRL>(acc[x].z)*eb;
    acc[x].w = acc[x].w*ea + dpp_mov<CTRL>(acc[x].w)*eb;
  }
  m = M;
}

// ---------------- K1: qkvg (LN(seq) + projections) ----------------
__global__ __launch_bounds__(256, 3) void k_qkvg(
    const float* __restrict__ seq, const float* __restrict__ lsg, const float* __restrict__ lsb,
    const float* __restrict__ Wq, const float* __restrict__ Wk, const float* __restrict__ Wv,
    const float* __restrict__ Wg, const float* __restrict__ bg,
    float* __restrict__ Qw, float* __restrict__ Kw, float* __restrict__ Vw, float* __restrict__ Gw) {
  __shared__ __align__(16) float As[256*36];
  int t = threadIdx.x;
  int blk = blockIdx.x;
  int m0 = (blk >> 3) * 32;
  int y = blk & 7;
  {
    int r = t >> 3, c0 = t & 7;
    const float* srow = seq + (size_t)(m0 + r) * 256;
    float4 v[8];
    float s = 0.f, sq = 0.f;
#pragma unroll
    for (int qq = 0; qq < 8; ++qq) {
      v[qq] = *(const float4*)(srow + 4*(c0 + 8*qq));
      s += v[qq].x + v[qq].y + v[qq].z + v[qq].w;
      sq = fmaf(v[qq].x, v[qq].x, sq); sq = fmaf(v[qq].y, v[qq].y, sq);
      sq = fmaf(v[qq].z, v[qq].z, sq); sq = fmaf(v[qq].w, v[qq].w, sq);
    }
#pragma unroll
    for (int mm = 1; mm < 8; mm <<= 1) { s += __shfl_xor(s, mm); sq += __shfl_xor(sq, mm); }
    float mu = s * (1.f/256.f);
    float var = sq * (1.f/256.f) - mu*mu;
    float rstd = rsqrtf(var + 1e-5f);
#pragma unroll
    for (int qq = 0; qq < 8; ++qq) {
      int c4 = c0 + 8*qq;
      float4 g  = *(const float4*)(lsg + 4*c4);
      float4 bb = *(const float4*)(lsb + 4*c4);
      float* dp = As + 4*c4*36 + r;
      dp[0]   = (v[qq].x - mu)*rstd*g.x + bb.x;
      dp[36]  = (v[qq].y - mu)*rstd*g.y + bb.y;
      dp[72]  = (v[qq].z - mu)*rstd*g.z + bb.z;
      dp[108] = (v[qq].w - mu)*rstd*g.w + bb.w;
    }
  }
  __syncthreads();
  const float* Wm = (y < 2) ? Wq : (y < 4) ? Wk : (y < 6) ? Wv : Wg;
  int cb = (y & 1) * 128;
  int rg = t >> 5, cg2 = t & 31;
  const float* bp = Wm + cb + 4*cg2;
  const float* ap = As + 4*rg;
  float4 a0 = {0,0,0,0}, a1 = {0,0,0,0}, a2 = {0,0,0,0}, a3 = {0,0,0,0};
#pragma unroll 4
  for (int p = 0; p < 256; ++p) {
    float4 a  = *(const float4*)(ap + p*36);
    float4 bv = *(const float4*)(bp + p*256);
    a0.x = fmaf(a.x, bv.x, a0.x); a0.y = fmaf(a.x, bv.y, a0.y);
    a0.z = fmaf(a.x, bv.z, a0.z); a0.w = fmaf(a.x, bv.w, a0.w);
    a1.x = fmaf(a.y, bv.x, a1.x); a1.y = fmaf(a.y, bv.y, a1.y);
    a1.z = fmaf(a.y, bv.z, a1.z); a1.w = fmaf(a.y, bv.w, a1.w);
    a2.x = fmaf(a.z, bv.x, a2.x); a2.y = fmaf(a.z, bv.y, a2.y);
    a2.z = fmaf(a.z, bv.z, a2.z); a2.w = fmaf(a.z, bv.w, a2.w);
    a3.x = fmaf(a.w, bv.x, a3.x); a3.y = fmaf(a.w, bv.y, a3.y);
    a3.z = fmaf(a.w, bv.z, a3.z); a3.w = fmaf(a.w, bv.w, a3.w);
  }
  int mat = y >> 1;
  int col = cb + 4*cg2;
  float* outp = (mat == 0) ? Qw : (mat == 1) ? Kw : (mat == 2) ? Vw : Gw;
  if (mat == 0) {
    const float qs = 0.17677669529663687f;
    a0.x*=qs; a0.y*=qs; a0.z*=qs; a0.w*=qs;
    a1.x*=qs; a1.y*=qs; a1.z*=qs; a1.w*=qs;
    a2.x*=qs; a2.y*=qs; a2.z*=qs; a2.w*=qs;
    a3.x*=qs; a3.y*=qs; a3.z*=qs; a3.w*=qs;
  }
  if (mat == 3) {
    float4 g4 = *(const float4*)(bg + col);
    a0.x = 1.f/(1.f+__expf(-(a0.x+g4.x))); a0.y = 1.f/(1.f+__expf(-(a0.y+g4.y)));
    a0.z = 1.f/(1.f+__expf(-(a0.z+g4.z))); a0.w = 1.f/(1.f+__expf(-(a0.w+g4.w)));
    a1.x = 1.f/(1.f+__expf(-(a1.x+g4.x))); a1.y = 1.f/(1.f+__expf(-(a1.y+g4.y)));
    a1.z = 1.f/(1.f+__expf(-(a1.z+g4.z))); a1.w = 1.f/(1.f+__expf(-(a1.w+g4.w)));
    a2.x = 1.f/(1.f+__expf(-(a2.x+g4.x))); a2.y = 1.f/(1.f+__expf(-(a2.y+g4.y)));
    a2.z = 1.f/(1.f+__expf(-(a2.z+g4.z))); a2.w = 1.f/(1.f+__expf(-(a2.w+g4.w)));
    a3.x = 1.f/(1.f+__expf(-(a3.x+g4.x))); a3.y = 1.f/(1.f+__expf(-(a3.y+g4.y)));
    a3.z = 1.f/(1.f+__expf(-(a3.z+g4.z))); a3.w = 1.f/(1.f+__expf(-(a3.w+g4.w)));
  }
  int orow = m0 + 4*rg;
  *(float4*)(outp + (size_t)(orow+0)*256 + col) = a0;
  *(float4*)(outp + (size_t)(orow+1)*256 + col) = a1;
  *(float4*)(outp + (size_t)(orow+2)*256 + col) = a2;
  *(float4*)(outp + (size_t)(orow+3)*256 + col) = a3;
}

// ---------------- K2: FUSED pair-LN/bias + attention (wave-specialized, 4 i-rows) ----------------
// 512 blocks x 512 thr. Waves 0-3: attn (ip=w&1 -> 2 i-rows/lane-pair, jset=w>>1).
// Waves 4-7: bias producer (16 groups: il=g>>2 in 0..3, jjbase=(g&3)*8, 8 rows/tile).
// All 8 waves co-stage K/V (rows 4w..4w+3).
#define KVS 292
__global__ __launch_bounds__(512, 2) void k_fused(
    const float* __restrict__ Qw, const float* __restrict__ Kw, const float* __restrict__ Vw,
    const float* __restrict__ Gw, const float* __restrict__ lpg, const float* __restrict__ lpb,
    const float* __restrict__ Wb, const float* __restrict__ pair, float* __restrict__ prew) {
  __shared__ __align__(16) float Kb[2][32*KVS];
  __shared__ __align__(16) float Vb[2][32*KVS];
  __shared__ __align__(16) float Bbuf[2][1024];   // [(il*32+jl)*8+n], il 0..3
  float* scr = &Kb[0][0];                          // epilogue overlay (Kb[0] dead: last tile uses buf 1)

  int t = threadIdx.x, lane = t & 63, w = t >> 6;   // w 0..7
  int b = blockIdx.x >> 7, i0 = (blockIdx.x & 127) << 2;

  const float* Kg = Kw + (size_t)(b*512)*256;
  const float* Vg = Vw + (size_t)(b*512)*256;
  float4 sk[4], sv[4];
  int woff = (lane >> 3)*36 + (lane & 7)*4;

  // attn-role state (valid only for w<4)
  int n = lane >> 3, js = lane & 7;
  int ip = w & 1, jset = (w >> 1) & 1;
  int ila = 2*ip, ilb = ila + 1;
  size_t qra = (size_t)(b*512 + i0 + ila);
  size_t qrb = qra + 1;
  float4 fa, fb;
  float ma = -1e30f, la = 0.f, mb2 = -1e30f, lb2 = 0.f;

#define SLOAD(tn) { \
    const float* ks_ = Kg + ((size_t)(tn)*32 + 4*w)*256 + 4*lane; \
    const float* vs_ = Vg + ((size_t)(tn)*32 + 4*w)*256 + 4*lane; \
    sk[0] = *(const float4*)(ks_);       sk[1] = *(const float4*)(ks_ + 256); \
    sk[2] = *(const float4*)(ks_ + 512); sk[3] = *(const float4*)(ks_ + 768); \
    sv[0] = *(const float4*)(vs_);       sv[1] = *(const float4*)(vs_ + 256); \
    sv[2] = *(const float4*)(vs_ + 512); sv[3] = *(const float4*)(vs_ + 768); \
  }
#define SWRITE(tn) { int bf_ = (tn) & 1; \
    float* kd_ = &Kb[bf_][(4*w)*KVS + woff]; \
    *(float4*)(kd_)         = sk[0]; *(float4*)(kd_ + KVS)   = sk[1]; \
    *(float4*)(kd_ + 2*KVS) = sk[2]; *(float4*)(kd_ + 3*KVS) = sk[3]; \
    float* vd_ = &Vb[bf_][(4*w)*KVS + woff]; \
    *(float4*)(vd_)         = sv[0]; *(float4*)(vd_ + KVS)   = sv[1]; \
    *(float4*)(vd_ + 2*KVS) = sv[2]; *(float4*)(vd_ + 3*KVS) = sv[3]; \
  }

  if (w < 4) {
    // ================= ATTN ROLE =================
    float4 qa[8], qb[8];
    {
      const float* pa = Qw + qra*256 + n*32;
      const float* pb = Qw + qrb*256 + n*32;
#pragma unroll
      for (int x = 0; x < 8; ++x) { qa[x] = *(const float4*)(pa + 4*x); qb[x] = *(const float4*)(pb + 4*x); }
    }
    float4 acca[8], accb[8];
#pragma unroll
    for (int x = 0; x < 8; ++x) { acca[x] = make_float4(0,0,0,0); accb[x] = make_float4(0,0,0,0); }

    SLOAD(0);
    SWRITE(0);
    __syncthreads();

    for (int tt = 0; tt < 16; ++tt) {
      int cur = tt & 1;
      if (tt < 15) SLOAD(tt+1);
      const float* Kt = Kb[cur];
      const float* Vt = Vb[cur];
      const float* Bt = Bbuf[cur];
#pragma unroll
      for (int jj2 = 0; jj2 < 2; ++jj2) {
        int jl = jset*16 + jj2*8 + js;
        float bba = Bt[(ila*32 + jl)*8 + n];
        float bbb = Bt[(ilb*32 + jl)*8 + n];
        const float* kp = Kt + jl*KVS + n*36;
        float da = 0.f, db = 0.f;
#pragma unroll
        for (int x = 0; x < 8; ++x) {
          float4 kk = *(const float4*)(kp + 4*x);
          da = dot4(qa[x], kk, da); db = dot4(qb[x], kk, db);
        }
        float lga = da + bba, lgb = db + bbb;
        if (lga > ma) {
          float sc = __expf(ma - lga);
          la *= sc;
#pragma unroll
          for (int x = 0; x < 8; ++x) {
            acca[x].x *= sc; acca[x].y *= sc; acca[x].z *= sc; acca[x].w *= sc;
          }
          ma = lga;
        }
        if (lgb > mb2) {
          float sc = __expf(mb2 - lgb);
          lb2 *= sc;
#pragma unroll
          for (int x = 0; x < 8; ++x) {
            accb[x].x *= sc; accb[x].y *= sc; accb[x].z *= sc; accb[x].w *= sc;
          }
          mb2 = lgb;
        }
        float pa_ = __expf(lga - ma), pb_ = __expf(lgb - mb2);
        la += pa_; lb2 += pb_;
        const float* vp = Vt + jl*KVS + n*36;
#pragma unroll
        for (int x = 0; x < 8; ++x) {
          float4 vv = *(const float4*)(vp + 4*x);
          acca[x].x = fmaf(pa_, vv.x, acca[x].x); acca[x].y = fmaf(pa_, vv.y, acca[x].y);
          acca[x].z = fmaf(pa_, vv.z, acca[x].z); acca[x].w = fmaf(pa_, vv.w, acca[x].w);
          accb[x].x = fmaf(pb_, vv.x, accb[x].x); accb[x].y = fmaf(pb_, vv.y, accb[x].y);
          accb[x].z = fmaf(pb_, vv.z, accb[x].z); accb[x].w = fmaf(pb_, vv.w, accb[x].w);
        }
      }
      if (tt < 15) SWRITE(tt+1);
      __syncthreads();
    }

    merge_dpp<0xB1>(ma, la, acca);   merge_dpp<0xB1>(mb2, lb2, accb);
    merge_dpp<0x4E>(ma, la, acca);   merge_dpp<0x4E>(mb2, lb2, accb);
    merge_dpp<0x141>(ma, la, acca);  merge_dpp<0x141>(mb2, lb2, accb);
    fa = sel8_f4(acca, js);
    fb = sel8_f4(accb, js);
  } else {
    // ================= BIAS PRODUCER ROLE =================
    int w4 = w - 4;
    int grp = lane >> 4, f = lane & 15;
    int g = w4*4 + grp;                 // 0..15
    int il = g >> 2;                    // 0..3
    int jjbase = (g & 3) * 8;           // 0,8,16,24

    float wp[64];
    float cg[8] = {0,0,0,0,0,0,0,0}, cbv[8] = {0,0,0,0,0,0,0,0};
#pragma unroll
    for (int q = 0; q < 4; ++q) {
      int kA = 4*f + q, kB = 64 + 4*f + q;
      float gA = lpg[kA], bA = lpb[kA];
      float gB = lpg[kB], bB = lpb[kB];
      float4 uA0 = *(const float4*)(Wb + kA*8);
      float4 uA1 = *(const float4*)(Wb + kA*8 + 4);
      float4 uB0 = *(const float4*)(Wb + kB*8);
      float4 uB1 = *(const float4*)(Wb + kB*8 + 4);
      wp[q*8+0] = gA*uA0.x; cg[0] += wp[q*8+0]; cbv[0] = fmaf(bA, uA0.x, cbv[0]);
      wp[q*8+1] = gA*uA0.y; cg[1] += wp[q*8+1]; cbv[1] = fmaf(bA, uA0.y, cbv[1]);
      wp[q*8+2] = gA*uA0.z; cg[2] += wp[q*8+2]; cbv[2] = fmaf(bA, uA0.z, cbv[2]);
      wp[q*8+3] = gA*uA0.w; cg[3] += wp[q*8+3]; cbv[3] = fmaf(bA, uA0.w, cbv[3]);
      wp[q*8+4] = gA*uA1.x; cg[4] += wp[q*8+4]; cbv[4] = fmaf(bA, uA1.x, cbv[4]);
      wp[q*8+5] = gA*uA1.y; cg[5] += wp[q*8+5]; cbv[5] = fmaf(bA, uA1.y, cbv[5]);
      wp[q*8+6] = gA*uA1.z; cg[6] += wp[q*8+6]; cbv[6] = fmaf(bA, uA1.z, cbv[6]);
      wp[q*8+7] = gA*uA1.w; cg[7] += wp[q*8+7]; cbv[7] = fmaf(bA, uA1.w, cbv[7]);
      int qb8 = (4+q)*8;
      wp[qb8+0] = gB*uB0.x; cg[0] += wp[qb8+0]; cbv[0] = fmaf(bB, uB0.x, cbv[0]);
      wp[qb8+1] = gB*uB0.y; cg[1] += wp[qb8+1]; cbv[1] = fmaf(bB, uB0.y, cbv[1]);
      wp[qb8+2] = gB*uB0.z; cg[2] += wp[qb8+2]; cbv[2] = fmaf(bB, uB0.z, cbv[2]);
      wp[qb8+3] = gB*uB0.w; cg[3] += wp[qb8+3]; cbv[3] = fmaf(bB, uB0.w, cbv[3]);
      wp[qb8+4] = gB*uB1.x; cg[4] += wp[qb8+4]; cbv[4] = fmaf(bB, uB1.x, cbv[4]);
      wp[qb8+5] = gB*uB1.y; cg[5] += wp[qb8+5]; cbv[5] = fmaf(bB, uB1.y, cbv[5]);
      wp[qb8+6] = gB*uB1.z; cg[6] += wp[qb8+6]; cbv[6] = fmaf(bB, uB1.z, cbv[6]);
      wp[qb8+7] = gB*uB1.w; cg[7] += wp[qb8+7]; cbv[7] = fmaf(bB, uB1.w, cbv[7]);
    }
#pragma unroll
    for (int n2 = 0; n2 < 8; ++n2) { cg[n2] = red16(cg[n2]); cbv[n2] = red16(cbv[n2]); }
    float cgsel, cbsel;
    SEL8(cg, f, cgsel);
    SEL8(cbv, f, cbsel);

    size_t prowbase = (size_t)(b*512 + i0 + il) * 512;

#define PROCB(X0, X1, JJ, PB) { \
    float s_  = X0.x + X0.y + X0.z + X0.w + X1.x + X1.y + X1.z + X1.w; \
    float sq_ = X0.x*X0.x; \
    sq_ = fmaf(X0.y, X0.y, sq_); sq_ = fmaf(X0.z, X0.z, sq_); sq_ = fmaf(X0.w, X0.w, sq_); \
    sq_ = fmaf(X1.x, X1.x, sq_); sq_ = fmaf(X1.y, X1.y, sq_); \
    sq_ = fmaf(X1.z, X1.z, sq_); sq_ = fmaf(X1.w, X1.w, sq_); \
    float dd_[8]; \
    _Pragma("unroll") \
    for (int n2 = 0; n2 < 8; ++n2) { \
      float d_ = X0.x * wp[n2]; \
      d_ = fmaf(X0.y, wp[8+n2],  d_); \
      d_ = fmaf(X0.z, wp[16+n2], d_); \
      d_ = fmaf(X0.w, wp[24+n2], d_); \
      d_ = fmaf(X1.x, wp[32+n2], d_); \
      d_ = fmaf(X1.y, wp[40+n2], d_); \
      d_ = fmaf(X1.z, wp[48+n2], d_); \
      d_ = fmaf(X1.w, wp[56+n2], d_); \
      dd_[n2] = d_; \
    } \
    s_  = red16(s_); \
    sq_ = red16(sq_); \
    _Pragma("unroll") \
    for (int n2 = 0; n2 < 8; ++n2) dd_[n2] = red16(dd_[n2]); \
    float mu_ = s_ * (1.f/128.f); \
    float var_ = fmaf(sq_, 1.f/128.f, -mu_*mu_); \
    float rstd_ = rsqrtf(var_ + 1e-5f); \
    if (f < 8) { \
      float dv_; \
      SEL8(dd_, f, dv_); \
      Bbuf[PB][(il*32 + (JJ))*8 + f] = fmaf(rstd_, fmaf(-mu_, cgsel, dv_), cbsel); \
    } \
  }

#define LOADB(D0, D1, SB, J0G) { \
    _Pragma("unroll") \
    for (int q2 = 0; q2 < 4; ++q2) { \
      const float* r_ = pair + (prowbase + (size_t)(J0G) + (size_t)(jjbase + (SB)*4 + q2))*128 + 4*f; \
      D0[q2] = *(const float4*)r_; D1[q2] = *(const float4*)(r_ + 64); \
    } }
#define PROCB4(S0, S1, SB, PB) { \
    _Pragma("unroll") \
    for (int q2 = 0; q2 < 4; ++q2) { PROCB(S0[q2], S1[q2], (jjbase + (SB)*4 + q2), PB) } }

#define PRODUCE(PB, J0G) { \
    float4 XA0[4], XA1[4], XB0[4], XB1[4]; \
    LOADB(XA0, XA1, 0, J0G) \
    LOADB(XB0, XB1, 1, J0G) \
    PROCB4(XA0, XA1, 0, PB) \
    PROCB4(XB0, XB1, 1, PB) \
  }

    SLOAD(0);
    PRODUCE(0, 0)
    SWRITE(0);
    __syncthreads();

    for (int tt = 0; tt < 16; ++tt) {
      if (tt < 15) {
        SLOAD(tt+1);
        PRODUCE((tt+1) & 1, (tt+1)*32)
        SWRITE(tt+1);
      }
      __syncthreads();
    }
#undef PRODUCE
#undef PROCB4
#undef LOADB
#undef PROCB
  }
#undef SLOAD
#undef SWRITE

  // ---- common epilogue (ALL waves run the barrier) ----
  if (w < 4 && jset == 1) {
    int base = (ip*8 + n)*68;
    *(float4*)(scr + base + 4*js) = fa;
    *(float4*)(scr + base + 32 + 4*js) = fb;
    if (js == 0) { scr[base+64] = ma; scr[base+65] = la; scr[base+66] = mb2; scr[base+67] = lb2; }
  }
  __syncthreads();
  if (w < 4 && jset == 0) {
    int base = (ip*8 + n)*68;
    float4 a2 = *(const float4*)(scr + base + 4*js);
    float4 b2 = *(const float4*)(scr + base + 32 + 4*js);
    float m2a = scr[base+64], l2a = scr[base+65];
    float m2b = scr[base+66], l2b = scr[base+67];
    {
      float M = fmaxf(ma, m2a);
      float ea = __expf(ma - M), eb = __expf(m2a - M);
      float inv = 1.f / (la*ea + l2a*eb);
      float4 g4 = *(const float4*)(Gw + qra*256 + n*32 + 4*js);
      float4 r;
      r.x = (fa.x*ea + a2.x*eb) * inv * g4.x;
      r.y = (fa.y*ea + a2.y*eb) * inv * g4.y;
      r.z = (fa.z*ea + a2.z*eb) * inv * g4.z;
      r.w = (fa.w*ea + a2.w*eb) * inv * g4.w;
      *(float4*)(prew + qra*256 + n*32 + 4*js) = r;
    }
    {
      float M = fmaxf(mb2, m2b);
      float ea = __expf(mb2 - M), eb = __expf(m2b - M);
      float inv = 1.f / (lb2*ea + l2b*eb);
      float4 g4 = *(const float4*)(Gw + qrb*256 + n*32 + 4*js);
      float4 r;
      r.x = (fb.x*ea + b2.x*eb) * inv * g4.x;
      r.y = (fb.y*ea + b2.y*eb) * inv * g4.y;
      r.z = (fb.z*ea + b2.z*eb) * inv * g4.z;
      r.w = (fb.w*ea + b2.w*eb) * inv * g4.w;
      *(float4*)(prew + qrb*256 + n*32 + 4*js) = r;
    }
  }
}

// ---------------- K3: output projection ----------------
__global__ __launch_bounds__(256) void k_out(
    const float* __restrict__ prew, const float* __restrict__ Wo, const float* __restrict__ bo,
    float* __restrict__ out) {
  __shared__ __align__(16) float As[256*36];
  int t = threadIdx.x;
  int m0 = blockIdx.x * 32;
  int y = blockIdx.y;
  {
    int r = t >> 3, c0 = t & 7;
    const float* srow = prew + (size_t)(m0 + r)*256;
#pragma unroll
    for (int qq = 0; qq < 8; ++qq) {
      int c4 = c0 + 8*qq;
      float4 v = *(const float4*)(srow + 4*c4);
      float* dp = As + 4*c4*36 + r;
      dp[0] = v.x; dp[36] = v.y; dp[72] = v.z; dp[108] = v.w;
    }
  }
  __syncthreads();
  int cb = y*128;
  int rg = t >> 5, cg2 = t & 31;
  int col = cb + 4*cg2;
  const float* bp = Wo + col;
  const float* ap = As + 4*rg;
  float4 a0 = {0,0,0,0}, a1 = {0,0,0,0}, a2 = {0,0,0,0}, a3 = {0,0,0,0};
#pragma unroll 4
  for (int p = 0; p < 256; ++p) {
    float4 a  = *(const float4*)(ap + p*36);
    float4 bv = *(const float4*)(bp + p*256);
    a0.x = fmaf(a.x, bv.x, a0.x); a0.y = fmaf(a.x, bv.y, a0.y);
    a0.z = fmaf(a.x, bv.z, a0.z); a0.w = fmaf(a.x, bv.w, a0.w);
    a1.x = fmaf(a.y, bv.x, a1.x); a1.y = fmaf(a.y, bv.y, a1.y);
    a1.z = fmaf(a.y, bv.z, a1.z); a1.w = fmaf(a.y, bv.w, a1.w);
    a2.x = fmaf(a.z, bv.x, a2.x); a2.y = fmaf(a.z, bv.y, a2.y);
    a2.z = fmaf(a.z, bv.z, a2.z); a2.w = fmaf(a.z, bv.w, a2.w);
    a3.x = fmaf(a.w, bv.x, a3.x); a3.y = fmaf(a.w, bv.y, a3.y);
    a3.z = fmaf(a.w, bv.z, a3.z); a3.w = fmaf(a.w, bv.w, a3.w);
  }
  float4 b4 = *(const float4*)(bo + col);
  a0.x += b4.x; a0.y += b4.y; a0.z += b4.z; a0.w += b4.w;
  a1.x += b4.x; a1.y += b4.y; a1.z += b4.z; a1.w += b4.w;
  a2.x += b4.x; a2.y += b4.y; a2.z += b4.z; a2.w += b4.w;
  a3.x += b4.x; a3.y += b4.y; a3.z += b4.z; a3.w += b4.w;
  int orow = m0 + 4*rg;
  *(float4*)(out + (size_t)(orow+0)*256 + col) = a0;
  *(float4*)(out + (size_t)(orow+1)*256 + col) = a1;
  *(float4*)(out + (size_t)(orow+2)*256 + col) = a2;
  *(float4*)(out + (size_t)(orow+3)*256 + col) = a3;
}

extern "C" void kernel_launch(void* const* d_in, const int* in_sizes, int n_in,
                              void* d_out, int out_size, void* d_ws, size_t ws_size,
                              hipStream_t stream) {
  const float* seq  = (const float*)d_in[0];
  const float* pair = (const float*)d_in[1];
  const float* lsg  = (const float*)d_in[2];
  const float* lsb  = (const float*)d_in[3];
  const float* lpg  = (const float*)d_in[4];
  const float* lpb  = (const float*)d_in[5];
  const float* Wb   = (const float*)d_in[6];
  const float* Wq   = (const float*)d_in[7];
  const float* Wk   = (const float*)d_in[8];
  const float* Wv   = (const float*)d_in[9];
  const float* Wg   = (const float*)d_in[10];
  const float* bg   = (const float*)d_in[11];
  const float* Wo   = (const float*)d_in[12];
  const float* bo   = (const float*)d_in[13];
  float* ws   = (float*)d_ws;
  float* Qw   = ws + OFF_Q;
  float* Kw   = ws + OFF_K;
  float* Vw   = ws + OFF_V;
  float* Gw   = ws + OFF_G;
  float* prew = ws + OFF_PRE;
  float* out  = (float*)d_out;

  hipLaunchKernelGGL(k_qkvg, dim3(512), dim3(256), 0, stream,
                     seq, lsg, lsb, Wq, Wk, Wv, Wg, bg, Qw, Kw, Vw, Gw);
  hipLaunchKernelGGL(k_fused, dim3(512), dim3(512), 0, stream,
                     Qw, Kw, Vw, Gw, lpg, lpb, Wb, pair, prew);
  hipLaunchKernelGGL(k_out, dim3(64, 2), dim3(256), 0, stream,
                     prew, Wo, bo, out);
}

// Round 15
// 202.637 us; speedup vs baseline: 1.1097x; 1.1097x over previous
//
#include <hip/hip_runtime.h>
#include <hip/hip_bf16.h>
#include <math.h>

// ws offsets (floats)
#define OFF_Q    0
#define OFF_K    (524288)
#define OFF_V    (524288*2)
#define OFF_G    (524288*3)
#define OFF_PRE  (524288*4)
#define OFF_BIAS (524288*5)

// ---------- DPP helpers ----------
template <int CTRL>
__device__ __forceinline__ float dpp_mov(float x) {
  return __int_as_float(__builtin_amdgcn_update_dpp(0, __float_as_int(x), CTRL, 0xF, 0xF, true));
}
template <int CTRL>
__device__ __forceinline__ float dpp_add(float x) { return x + dpp_mov<CTRL>(x); }
__device__ __forceinline__ float red16(float v) {
  v = dpp_add<0xB1>(v);    // xor 1
  v = dpp_add<0x4E>(v);    // xor 2
  v = dpp_add<0x141>(v);   // row_half_mirror (xor 7)
  v = dpp_add<0x140>(v);   // row_mirror      (xor 15)
  return v;
}

#define SEL8(a, f, out) do { \
  float _s0 = ((f)&1) ? a[1] : a[0]; \
  float _s1 = ((f)&1) ? a[3] : a[2]; \
  float _s2 = ((f)&1) ? a[5] : a[4]; \
  float _s3 = ((f)&1) ? a[7] : a[6]; \
  float _t0 = ((f)&2) ? _s1 : _s0; \
  float _t1 = ((f)&2) ? _s3 : _s2; \
  out = ((f)&4) ? _t1 : _t0; \
} while(0)

__device__ __forceinline__ float4 sel8_f4(const float4* a, int f) {
  float4 s0 = (f&1) ? a[1] : a[0];
  float4 s1 = (f&1) ? a[3] : a[2];
  float4 s2 = (f&1) ? a[5] : a[4];
  float4 s3 = (f&1) ? a[7] : a[6];
  float4 t0 = (f&2) ? s1 : s0;
  float4 t1 = (f&2) ? s3 : s2;
  return (f&4) ? t1 : t0;
}

__device__ __forceinline__ float dot4(float4 a, float4 b, float acc) {
  acc = fmaf(a.x, b.x, acc); acc = fmaf(a.y, b.y, acc);
  acc = fmaf(a.z, b.z, acc); return fmaf(a.w, b.w, acc);
}

template <int CTRL>
__device__ __forceinline__ void merge_dpp(float& m, float& l, float4* acc) {
  float m2 = dpp_mov<CTRL>(m);
  float l2 = dpp_mov<CTRL>(l);
  float M = fmaxf(m, m2);
  float ea = __expf(m - M), eb = __expf(m2 - M);
  l = l*ea + l2*eb;
#pragma unroll
  for (int x = 0; x < 8; ++x) {
    acc[x].x = acc[x].x*ea + dpp_mov<CTRL>(acc[x].x)*eb;
    acc[x].y = acc[x].y*ea + dpp_mov<CTRL>(acc[x].y)*eb;
    acc[x].z = acc[x].z*ea + dpp_mov<CTRL>(acc[x].z)*eb;
    acc[x].w = acc[x].w*ea + dpp_mov<CTRL>(acc[x].w)*eb;
  }
  m = M;
}

// ---------------- K1: mega — blocks 0..511 bias (grid-strided), blocks 512..1023 qkvg ----------------
__global__ __launch_bounds__(256, 3) void k_mega(
    const float* __restrict__ seq, const float* __restrict__ lsg, const float* __restrict__ lsb,
    const float* __restrict__ lpg, const float* __restrict__ lpb, const float* __restrict__ Wb,
    const float* __restrict__ Wq, const float* __restrict__ Wk, const float* __restrict__ Wv,
    const float* __restrict__ Wg, const float* __restrict__ bg, const float* __restrict__ pair,
    float* __restrict__ Qw, float* __restrict__ Kw, float* __restrict__ Vw, float* __restrict__ Gw,
    __hip_bfloat16* __restrict__ biasw) {
  __shared__ __align__(16) float As[256*36];
  int t = threadIdx.x;
  int blk = blockIdx.x;

  if (blk >= 512) {
    // ---- qkvg path ----
    int kb = blk - 512;
    int m0 = (kb >> 3) * 32;
    int y = kb & 7;
    {
      int r = t >> 3, c0 = t & 7;
      const float* srow = seq + (size_t)(m0 + r) * 256;
      float4 v[8];
      float s = 0.f, sq = 0.f;
#pragma unroll
      for (int qq = 0; qq < 8; ++qq) {
        v[qq] = *(const float4*)(srow + 4*(c0 + 8*qq));
        s += v[qq].x + v[qq].y + v[qq].z + v[qq].w;
        sq = fmaf(v[qq].x, v[qq].x, sq); sq = fmaf(v[qq].y, v[qq].y, sq);
        sq = fmaf(v[qq].z, v[qq].z, sq); sq = fmaf(v[qq].w, v[qq].w, sq);
      }
#pragma unroll
      for (int mm = 1; mm < 8; mm <<= 1) { s += __shfl_xor(s, mm); sq += __shfl_xor(sq, mm); }
      float mu = s * (1.f/256.f);
      float var = sq * (1.f/256.f) - mu*mu;
      float rstd = rsqrtf(var + 1e-5f);
#pragma unroll
      for (int qq = 0; qq < 8; ++qq) {
        int c4 = c0 + 8*qq;
        float4 g  = *(const float4*)(lsg + 4*c4);
        float4 bb = *(const float4*)(lsb + 4*c4);
        float* dp = As + 4*c4*36 + r;
        dp[0]   = (v[qq].x - mu)*rstd*g.x + bb.x;
        dp[36]  = (v[qq].y - mu)*rstd*g.y + bb.y;
        dp[72]  = (v[qq].z - mu)*rstd*g.z + bb.z;
        dp[108] = (v[qq].w - mu)*rstd*g.w + bb.w;
      }
    }
    __syncthreads();
    const float* Wm = (y < 2) ? Wq : (y < 4) ? Wk : (y < 6) ? Wv : Wg;
    int cb = (y & 1) * 128;
    int rg = t >> 5, cg2 = t & 31;
    const float* bp = Wm + cb + 4*cg2;
    const float* ap = As + 4*rg;
    float4 a0 = {0,0,0,0}, a1 = {0,0,0,0}, a2 = {0,0,0,0}, a3 = {0,0,0,0};
#pragma unroll 4
    for (int p = 0; p < 256; ++p) {
      float4 a  = *(const float4*)(ap + p*36);
      float4 bv = *(const float4*)(bp + p*256);
      a0.x = fmaf(a.x, bv.x, a0.x); a0.y = fmaf(a.x, bv.y, a0.y);
      a0.z = fmaf(a.x, bv.z, a0.z); a0.w = fmaf(a.x, bv.w, a0.w);
      a1.x = fmaf(a.y, bv.x, a1.x); a1.y = fmaf(a.y, bv.y, a1.y);
      a1.z = fmaf(a.y, bv.z, a1.z); a1.w = fmaf(a.y, bv.w, a1.w);
      a2.x = fmaf(a.z, bv.x, a2.x); a2.y = fmaf(a.z, bv.y, a2.y);
      a2.z = fmaf(a.z, bv.z, a2.z); a2.w = fmaf(a.z, bv.w, a2.w);
      a3.x = fmaf(a.w, bv.x, a3.x); a3.y = fmaf(a.w, bv.y, a3.y);
      a3.z = fmaf(a.w, bv.z, a3.z); a3.w = fmaf(a.w, bv.w, a3.w);
    }
    int mat = y >> 1;
    int col = cb + 4*cg2;
    float* outp = (mat == 0) ? Qw : (mat == 1) ? Kw : (mat == 2) ? Vw : Gw;
    if (mat == 0) {
      const float qs = 0.17677669529663687f;
      a0.x*=qs; a0.y*=qs; a0.z*=qs; a0.w*=qs;
      a1.x*=qs; a1.y*=qs; a1.z*=qs; a1.w*=qs;
      a2.x*=qs; a2.y*=qs; a2.z*=qs; a2.w*=qs;
      a3.x*=qs; a3.y*=qs; a3.z*=qs; a3.w*=qs;
    }
    if (mat == 3) {
      float4 g4 = *(const float4*)(bg + col);
      a0.x = 1.f/(1.f+__expf(-(a0.x+g4.x))); a0.y = 1.f/(1.f+__expf(-(a0.y+g4.y)));
      a0.z = 1.f/(1.f+__expf(-(a0.z+g4.z))); a0.w = 1.f/(1.f+__expf(-(a0.w+g4.w)));
      a1.x = 1.f/(1.f+__expf(-(a1.x+g4.x))); a1.y = 1.f/(1.f+__expf(-(a1.y+g4.y)));
      a1.z = 1.f/(1.f+__expf(-(a1.z+g4.z))); a1.w = 1.f/(1.f+__expf(-(a1.w+g4.w)));
      a2.x = 1.f/(1.f+__expf(-(a2.x+g4.x))); a2.y = 1.f/(1.f+__expf(-(a2.y+g4.y)));
      a2.z = 1.f/(1.f+__expf(-(a2.z+g4.z))); a2.w = 1.f/(1.f+__expf(-(a2.w+g4.w)));
      a3.x = 1.f/(1.f+__expf(-(a3.x+g4.x))); a3.y = 1.f/(1.f+__expf(-(a3.y+g4.y)));
      a3.z = 1.f/(1.f+__expf(-(a3.z+g4.z))); a3.w = 1.f/(1.f+__expf(-(a3.w+g4.w)));
    }
    int orow = m0 + 4*rg;
    *(float4*)(outp + (size_t)(orow+0)*256 + col) = a0;
    *(float4*)(outp + (size_t)(orow+1)*256 + col) = a1;
    *(float4*)(outp + (size_t)(orow+2)*256 + col) = a2;
    *(float4*)(outp + (size_t)(orow+3)*256 + col) = a3;
    return;
  }

  // ---- bias path: grid-strided rows ----
  int lane = t & 63, w = t >> 6;
  int grp = lane >> 4, f = lane & 15;

  float wp[64];
  float cg[8] = {0,0,0,0,0,0,0,0}, cbv[8] = {0,0,0,0,0,0,0,0};
#pragma unroll
  for (int q = 0; q < 4; ++q) {
    int kA = 4*f + q, kB = 64 + 4*f + q;
    float gA = lpg[kA], bA = lpb[kA];
    float gB = lpg[kB], bB = lpb[kB];
    float4 uA0 = *(const float4*)(Wb + kA*8);
    float4 uA1 = *(const float4*)(Wb + kA*8 + 4);
    float4 uB0 = *(const float4*)(Wb + kB*8);
    float4 uB1 = *(const float4*)(Wb + kB*8 + 4);
    wp[q*8+0] = gA*uA0.x; cg[0] += wp[q*8+0]; cbv[0] = fmaf(bA, uA0.x, cbv[0]);
    wp[q*8+1] = gA*uA0.y; cg[1] += wp[q*8+1]; cbv[1] = fmaf(bA, uA0.y, cbv[1]);
    wp[q*8+2] = gA*uA0.z; cg[2] += wp[q*8+2]; cbv[2] = fmaf(bA, uA0.z, cbv[2]);
    wp[q*8+3] = gA*uA0.w; cg[3] += wp[q*8+3]; cbv[3] = fmaf(bA, uA0.w, cbv[3]);
    wp[q*8+4] = gA*uA1.x; cg[4] += wp[q*8+4]; cbv[4] = fmaf(bA, uA1.x, cbv[4]);
    wp[q*8+5] = gA*uA1.y; cg[5] += wp[q*8+5]; cbv[5] = fmaf(bA, uA1.y, cbv[5]);
    wp[q*8+6] = gA*uA1.z; cg[6] += wp[q*8+6]; cbv[6] = fmaf(bA, uA1.z, cbv[6]);
    wp[q*8+7] = gA*uA1.w; cg[7] += wp[q*8+7]; cbv[7] = fmaf(bA, uA1.w, cbv[7]);
    int qb8 = (4+q)*8;
    wp[qb8+0] = gB*uB0.x; cg[0] += wp[qb8+0]; cbv[0] = fmaf(bB, uB0.x, cbv[0]);
    wp[qb8+1] = gB*uB0.y; cg[1] += wp[qb8+1]; cbv[1] = fmaf(bB, uB0.y, cbv[1]);
    wp[qb8+2] = gB*uB0.z; cg[2] += wp[qb8+2]; cbv[2] = fmaf(bB, uB0.z, cbv[2]);
    wp[qb8+3] = gB*uB0.w; cg[3] += wp[qb8+3]; cbv[3] = fmaf(bB, uB0.w, cbv[3]);
    wp[qb8+4] = gB*uB1.x; cg[4] += wp[qb8+4]; cbv[4] = fmaf(bB, uB1.x, cbv[4]);
    wp[qb8+5] = gB*uB1.y; cg[5] += wp[qb8+5]; cbv[5] = fmaf(bB, uB1.y, cbv[5]);
    wp[qb8+6] = gB*uB1.z; cg[6] += wp[qb8+6]; cbv[6] = fmaf(bB, uB1.z, cbv[6]);
    wp[qb8+7] = gB*uB1.w; cg[7] += wp[qb8+7]; cbv[7] = fmaf(bB, uB1.w, cbv[7]);
  }
#pragma unroll
  for (int n2 = 0; n2 < 8; ++n2) { cg[n2] = red16(cg[n2]); cbv[n2] = red16(cbv[n2]); }
  float cgsel, cbsel;
  SEL8(cg, f, cgsel);
  SEL8(cbv, f, cbsel);

  int gid = blk*16 + w*4 + grp;
  const float* rp0 = pair + (size_t)gid*128 + 4*f;   // + R_it*1048576
  __hip_bfloat16* bw0 = biasw + (size_t)gid*8 + f;   // + R_it*65536

#define PROCROW(X0, X1, IDX) { \
    float s_  = X0.x + X0.y + X0.z + X0.w + X1.x + X1.y + X1.z + X1.w; \
    float sq_ = X0.x*X0.x; \
    sq_ = fmaf(X0.y, X0.y, sq_); sq_ = fmaf(X0.z, X0.z, sq_); sq_ = fmaf(X0.w, X0.w, sq_); \
    sq_ = fmaf(X1.x, X1.x, sq_); sq_ = fmaf(X1.y, X1.y, sq_); \
    sq_ = fmaf(X1.z, X1.z, sq_); sq_ = fmaf(X1.w, X1.w, sq_); \
    float dd_[8]; \
    _Pragma("unroll") \
    for (int n2 = 0; n2 < 8; ++n2) { \
      float d_ = X0.x * wp[n2]; \
      d_ = fmaf(X0.y, wp[8+n2],  d_); \
      d_ = fmaf(X0.z, wp[16+n2], d_); \
      d_ = fmaf(X0.w, wp[24+n2], d_); \
      d_ = fmaf(X1.x, wp[32+n2], d_); \
      d_ = fmaf(X1.y, wp[40+n2], d_); \
      d_ = fmaf(X1.z, wp[48+n2], d_); \
      d_ = fmaf(X1.w, wp[56+n2], d_); \
      dd_[n2] = d_; \
    } \
    s_  = red16(s_); \
    sq_ = red16(sq_); \
    _Pragma("unroll") \
    for (int n2 = 0; n2 < 8; ++n2) dd_[n2] = red16(dd_[n2]); \
    float mu_ = s_ * (1.f/128.f); \
    float var_ = fmaf(sq_, 1.f/128.f, -mu_*mu_); \
    float rstd_ = rsqrtf(var_ + 1e-5f); \
    if (f < 8) { \
      float dv_; \
      SEL8(dd_, f, dv_); \
      bw0[(size_t)(IDX)*65536] = __float2bfloat16(fmaf(rstd_, fmaf(-mu_, cgsel, dv_), cbsel)); \
    } \
  }

  float4 A0[4], A1[4], B0[4], B1[4];
#pragma unroll
  for (int q = 0; q < 4; ++q) {
    const float* r = rp0 + (size_t)q*1048576;
    A0[q] = *(const float4*)r; A1[q] = *(const float4*)(r + 64);
  }
#pragma unroll
  for (int q = 0; q < 4; ++q) {
    const float* r = rp0 + (size_t)(4+q)*1048576;
    B0[q] = *(const float4*)r; B1[q] = *(const float4*)(r + 64);
  }

#define CHUNK(C0, C1, cc) { \
    _Pragma("unroll") \
    for (int q = 0; q < 4; ++q) PROCROW(C0[q], C1[q], (4*(cc) + q)); \
    if ((cc) + 2 < 32) { \
      _Pragma("unroll") \
      for (int q = 0; q < 4; ++q) { \
        const float* r = rp0 + (size_t)(4*((cc)+2) + q)*1048576; \
        C0[q] = *(const float4*)r; C1[q] = *(const float4*)(r + 64); \
      } \
    } \
  }

  for (int c = 0; c < 32; c += 2) {
    CHUNK(A0, A1, c)
    CHUNK(B0, B1, c+1)
  }
#undef CHUNK
#undef PROCROW
}

// ---------------- K2: attention — attn5 (dbuf, 1 barrier/tile, 292-pad), bf16 bias reads ----------------
__global__ __launch_bounds__(512) void k_attn5(
    const float* __restrict__ Qw, const float* __restrict__ Kw, const float* __restrict__ Vw,
    const float* __restrict__ Gw, const __hip_bfloat16* __restrict__ biasw, float* __restrict__ prew) {
  __shared__ __align__(16) float Kb[2][32*292];
  __shared__ __align__(16) float Vb[2][32*292];
  float* scr = &Kb[0][0];   // overlay for final merge (safe: Kb[0] dead after loop)

  int t = threadIdx.x, lane = t & 63, w = t >> 6;
  int b = blockIdx.x >> 6, i0 = (blockIdx.x & 63) << 3;
  int n = lane >> 3, js = lane & 7;
  int ip = w & 3, jset = w >> 2;
  int ila = 2*ip, ilb = ila + 1;
  size_t qra = (size_t)(b*512 + i0 + ila);
  size_t qrb = qra + 1;
  int jl0 = jset*16 + js;

  float4 qa[8], qb[8];
  {
    const float* pa = Qw + qra*256 + n*32;
    const float* pb = Qw + qrb*256 + n*32;
#pragma unroll
    for (int x = 0; x < 8; ++x) { qa[x] = *(const float4*)(pa + 4*x); qb[x] = *(const float4*)(pb + 4*x); }
  }
  float4 acca[8], accb[8];
#pragma unroll
  for (int x = 0; x < 8; ++x) { acca[x] = make_float4(0,0,0,0); accb[x] = make_float4(0,0,0,0); }
  float ma = -1e30f, la = 0.f, mb2 = -1e30f, lb2 = 0.f;

  const float* Kg = Kw + (size_t)(b*512)*256;
  const float* Vg = Vw + (size_t)(b*512)*256;
  const __hip_bfloat16* Bpa = biasw + ((size_t)(b*512 + i0 + ila)*512 + jl0)*8 + n;
  const __hip_bfloat16* Bpb = Bpa + 512*8;

  float4 sk[4], sv[4];
  int woff = (lane >> 3)*36 + (lane & 7)*4;   // seg-padded write offset

#define SLOAD(tn) { \
    const float* ks_ = Kg + ((size_t)(tn)*32 + 4*w)*256 + 4*lane; \
    const float* vs_ = Vg + ((size_t)(tn)*32 + 4*w)*256 + 4*lane; \
    sk[0] = *(const float4*)(ks_);       sk[1] = *(const float4*)(ks_ + 256); \
    sk[2] = *(const float4*)(ks_ + 512); sk[3] = *(const float4*)(ks_ + 768); \
    sv[0] = *(const float4*)(vs_);       sv[1] = *(const float4*)(vs_ + 256); \
    sv[2] = *(const float4*)(vs_ + 512); sv[3] = *(const float4*)(vs_ + 768); \
  }
#define SWRITE(tn) { int bf_ = (tn) & 1; \
    float* kd_ = &Kb[bf_][(4*w)*292 + woff]; \
    *(float4*)(kd_)       = sk[0]; *(float4*)(kd_ + 292) = sk[1]; \
    *(float4*)(kd_ + 584) = sk[2]; *(float4*)(kd_ + 876) = sk[3]; \
    float* vd_ = &Vb[bf_][(4*w)*292 + woff]; \
    *(float4*)(vd_)       = sv[0]; *(float4*)(vd_ + 292) = sv[1]; \
    *(float4*)(vd_ + 584) = sv[2]; *(float4*)(vd_ + 876) = sv[3]; \
  }

  SLOAD(0);
  SWRITE(0);
  __syncthreads();

  for (int tt = 0; tt < 16; ++tt) {
    int cur = tt & 1;
    if (tt < 15) SLOAD(tt+1);

    const float* Kt = Kb[cur];
    const float* Vt = Vb[cur];
    float bba0 = __bfloat162float(Bpa[tt*256]);
    float bba1 = __bfloat162float(Bpa[tt*256 + 64]);
    float bbb0 = __bfloat162float(Bpb[tt*256]);
    float bbb1 = __bfloat162float(Bpb[tt*256 + 64]);

    float lga0, lga1, lgb0, lgb1;
    {
      const float* kp = Kt + jl0*292 + n*36;
      float da = 0.f, db = 0.f;
#pragma unroll
      for (int x = 0; x < 8; ++x) {
        float4 kk = *(const float4*)(kp + 4*x);
        da = dot4(qa[x], kk, da); db = dot4(qb[x], kk, db);
      }
      lga0 = da + bba0; lgb0 = db + bbb0;
    }
    {
      const float* kp = Kt + (jl0+8)*292 + n*36;
      float da = 0.f, db = 0.f;
#pragma unroll
      for (int x = 0; x < 8; ++x) {
        float4 kk = *(const float4*)(kp + 4*x);
        da = dot4(qa[x], kk, da); db = dot4(qb[x], kk, db);
      }
      lga1 = da + bba1; lgb1 = db + bbb1;
    }
    {
      float tm = fmaxf(lga0, lga1);
      if (tm > ma) {
        float sc = __expf(ma - tm);
        la *= sc;
#pragma unroll
        for (int x = 0; x < 8; ++x) {
          acca[x].x *= sc; acca[x].y *= sc; acca[x].z *= sc; acca[x].w *= sc;
        }
        ma = tm;
      }
    }
    {
      float tm = fmaxf(lgb0, lgb1);
      if (tm > mb2) {
        float sc = __expf(mb2 - tm);
        lb2 *= sc;
#pragma unroll
        for (int x = 0; x < 8; ++x) {
          accb[x].x *= sc; accb[x].y *= sc; accb[x].z *= sc; accb[x].w *= sc;
        }
        mb2 = tm;
      }
    }
    float pa0 = __expf(lga0 - ma), pa1 = __expf(lga1 - ma);
    float pb0 = __expf(lgb0 - mb2), pb1 = __expf(lgb1 - mb2);
    la += pa0 + pa1; lb2 += pb0 + pb1;
    {
      const float* vp = Vt + jl0*292 + n*36;
#pragma unroll
      for (int x = 0; x < 8; ++x) {
        float4 vv = *(const float4*)(vp + 4*x);
        acca[x].x = fmaf(pa0, vv.x, acca[x].x); acca[x].y = fmaf(pa0, vv.y, acca[x].y);
        acca[x].z = fmaf(pa0, vv.z, acca[x].z); acca[x].w = fmaf(pa0, vv.w, acca[x].w);
        accb[x].x = fmaf(pb0, vv.x, accb[x].x); accb[x].y = fmaf(pb0, vv.y, accb[x].y);
        accb[x].z = fmaf(pb0, vv.z, accb[x].z); accb[x].w = fmaf(pb0, vv.w, accb[x].w);
      }
    }
    {
      const float* vp = Vt + (jl0+8)*292 + n*36;
#pragma unroll
      for (int x = 0; x < 8; ++x) {
        float4 vv = *(const float4*)(vp + 4*x);
        acca[x].x = fmaf(pa1, vv.x, acca[x].x); acca[x].y = fmaf(pa1, vv.y, acca[x].y);
        acca[x].z = fmaf(pa1, vv.z, acca[x].z); acca[x].w = fmaf(pa1, vv.w, acca[x].w);
        accb[x].x = fmaf(pb1, vv.x, accb[x].x); accb[x].y = fmaf(pb1, vv.y, accb[x].y);
        accb[x].z = fmaf(pb1, vv.z, accb[x].z); accb[x].w = fmaf(pb1, vv.w, accb[x].w);
      }
    }

    if (tt < 15) SWRITE(tt+1);
    __syncthreads();
  }
#undef SLOAD
#undef SWRITE

  merge_dpp<0xB1>(ma, la, acca);   merge_dpp<0xB1>(mb2, lb2, accb);
  merge_dpp<0x4E>(ma, la, acca);   merge_dpp<0x4E>(mb2, lb2, accb);
  merge_dpp<0x141>(ma, la, acca);  merge_dpp<0x141>(mb2, lb2, accb);

  float4 fa = sel8_f4(acca, js);
  float4 fb = sel8_f4(accb, js);

  if (jset == 1) {
    int base = (ip*8 + n)*68;
    *(float4*)(scr + base + 4*js) = fa;
    *(float4*)(scr + base + 32 + 4*js) = fb;
    if (js == 0) { scr[base+64] = ma; scr[base+65] = la; scr[base+66] = mb2; scr[base+67] = lb2; }
  }
  __syncthreads();
  if (jset == 0) {
    int base = (ip*8 + n)*68;
    float4 a2 = *(const float4*)(scr + base + 4*js);
    float4 b2 = *(const float4*)(scr + base + 32 + 4*js);
    float m2a = scr[base+64], l2a = scr[base+65];
    float m2b = scr[base+66], l2b = scr[base+67];
    {
      float M = fmaxf(ma, m2a);
      float ea = __expf(ma - M), eb = __expf(m2a - M);
      float inv = 1.f / (la*ea + l2a*eb);
      float4 g4 = *(const float4*)(Gw + qra*256 + n*32 + 4*js);
      float4 r;
      r.x = (fa.x*ea + a2.x*eb) * inv * g4.x;
      r.y = (fa.y*ea + a2.y*eb) * inv * g4.y;
      r.z = (fa.z*ea + a2.z*eb) * inv * g4.z;
      r.w = (fa.w*ea + a2.w*eb) * inv * g4.w;
      *(float4*)(prew + qra*256 + n*32 + 4*js) = r;
    }
    {
      float M = fmaxf(mb2, m2b);
      float ea = __expf(mb2 - M), eb = __expf(m2b - M);
      float inv = 1.f / (lb2*ea + l2b*eb);
      float4 g4 = *(const float4*)(Gw + qrb*256 + n*32 + 4*js);
      float4 r;
      r.x = (fb.x*ea + b2.x*eb) * inv * g4.x;
      r.y = (fb.y*ea + b2.y*eb) * inv * g4.y;
      r.z = (fb.z*ea + b2.z*eb) * inv * g4.z;
      r.w = (fb.w*ea + b2.w*eb) * inv * g4.w;
      *(float4*)(prew + qrb*256 + n*32 + 4*js) = r;
    }
  }
}

// ---------------- K3: output projection ----------------
__global__ __launch_bounds__(256) void k_out(
    const float* __restrict__ prew, const float* __restrict__ Wo, const float* __restrict__ bo,
    float* __restrict__ out) {
  __shared__ __align__(16) float As[256*36];
  int t = threadIdx.x;
  int m0 = blockIdx.x * 32;
  int y = blockIdx.y;
  {
    int r = t >> 3, c0 = t & 7;
    const float* srow = prew + (size_t)(m0 + r)*256;
#pragma unroll
    for (int qq = 0; qq < 8; ++qq) {
      int c4 = c0 + 8*qq;
      float4 v = *(const float4*)(srow + 4*c4);
      float* dp = As + 4*c4*36 + r;
      dp[0] = v.x; dp[36] = v.y; dp[72] = v.z; dp[108] = v.w;
    }
  }
  __syncthreads();
  int cb = y*128;
  int rg = t >> 5, cg2 = t & 31;
  int col = cb + 4*cg2;
  const float* bp = Wo + col;
  const float* ap = As + 4*rg;
  float4 a0 = {0,0,0,0}, a1 = {0,0,0,0}, a2 = {0,0,0,0}, a3 = {0,0,0,0};
#pragma unroll 4
  for (int p = 0; p < 256; ++p) {
    float4 a  = *(const float4*)(ap + p*36);
    float4 bv = *(const float4*)(bp + p*256);
    a0.x = fmaf(a.x, bv.x, a0.x); a0.y = fmaf(a.x, bv.y, a0.y);
    a0.z = fmaf(a.x, bv.z, a0.z); a0.w = fmaf(a.x, bv.w, a0.w);
    a1.x = fmaf(a.y, bv.x, a1.x); a1.y = fmaf(a.y, bv.y, a1.y);
    a1.z = fmaf(a.y, bv.z, a1.z); a1.w = fmaf(a.y, bv.w, a1.w);
    a2.x = fmaf(a.z, bv.x, a2.x); a2.y = fmaf(a.z, bv.y, a2.y);
    a2.z = fmaf(a.z, bv.z, a2.z); a2.w = fmaf(a.z, bv.w, a2.w);
    a3.x = fmaf(a.w, bv.x, a3.x); a3.y = fmaf(a.w, bv.y, a3.y);
    a3.z = fmaf(a.w, bv.z, a3.z); a3.w = fmaf(a.w, bv.w, a3.w);
  }
  float4 b4 = *(const float4*)(bo + col);
  a0.x += b4.x; a0.y += b4.y; a0.z += b4.z; a0.w += b4.w;
  a1.x += b4.x; a1.y += b4.y; a1.z += b4.z; a1.w += b4.w;
  a2.x += b4.x; a2.y += b4.y; a2.z += b4.z; a2.w += b4.w;
  a3.x += b4.x; a3.y += b4.y; a3.z += b4.z; a3.w += b4.w;
  int orow = m0 + 4*rg;
  *(float4*)(out + (size_t)(orow+0)*256 + col) = a0;
  *(float4*)(out + (size_t)(orow+1)*256 + col) = a1;
  *(float4*)(out + (size_t)(orow+2)*256 + col) = a2;
  *(float4*)(out + (size_t)(orow+3)*256 + col) = a3;
}

extern "C" void kernel_launch(void* const* d_in, const int* in_sizes, int n_in,
                              void* d_out, int out_size, void* d_ws, size_t ws_size,
                              hipStream_t stream) {
  const float* seq  = (const float*)d_in[0];
  const float* pair = (const float*)d_in[1];
  const float* lsg  = (const float*)d_in[2];
  const float* lsb  = (const float*)d_in[3];
  const float* lpg  = (const float*)d_in[4];
  const float* lpb  = (const float*)d_in[5];
  const float* Wb   = (const float*)d_in[6];
  const float* Wq   = (const float*)d_in[7];
  const float* Wk   = (const float*)d_in[8];
  const float* Wv   = (const float*)d_in[9];
  const float* Wg   = (const float*)d_in[10];
  const float* bg   = (const float*)d_in[11];
  const float* Wo   = (const float*)d_in[12];
  const float* bo   = (const float*)d_in[13];
  float* ws   = (float*)d_ws;
  float* Qw   = ws + OFF_Q;
  float* Kw   = ws + OFF_K;
  float* Vw   = ws + OFF_V;
  float* Gw   = ws + OFF_G;
  float* prew = ws + OFF_PRE;
  __hip_bfloat16* biasw = (__hip_bfloat16*)(ws + OFF_BIAS);
  float* out  = (float*)d_out;

  hipLaunchKernelGGL(k_mega, dim3(1024), dim3(256), 0, stream,
                     seq, lsg, lsb, lpg, lpb, Wb, Wq, Wk, Wv, Wg, bg, pair,
                     Qw, Kw, Vw, Gw, biasw);
  hipLaunchKernelGGL(k_attn5, dim3(256), dim3(512), 0, stream,
                     Qw, Kw, Vw, Gw, biasw, prew);
  hipLaunchKernelGGL(k_out, dim3(64, 2), dim3(256), 0, stream,
                     prew, Wo, bo, out);
}